// Round 8
// baseline (300.303 us; speedup 1.0000x reference)
//
#include <hip/hip_runtime.h>

// Problem constants: B=8, H=W=1024, V=35709, T=70789
#define BATCH 8
#define HWPIX (1024 * 1024)
#define NVERT 35709
#define NTRI  70789

typedef float        f32x4 __attribute__((ext_vector_type(4)));
typedef int          i32x4 __attribute__((ext_vector_type(4)));
typedef unsigned int u32x4 __attribute__((ext_vector_type(4)));

__device__ __forceinline__ unsigned q8(float x) {
    float v = x * 255.0f + 0.5f;
    v = fminf(fmaxf(v, 0.0f), 255.0f);
    return (unsigned)v;
}

// ---------------------------------------------------------------------------
// Prep stage 1: per-(batch,vertex) RGBX u8 color in one uint. ctab: [B,V].
// ---------------------------------------------------------------------------
__global__ __launch_bounds__(256) void quant_colors(
    const float* __restrict__ colors,   // [B,V,3]
    unsigned*    __restrict__ ctab)     // [B,V]
{
    const int v = blockIdx.x * blockDim.x + threadIdx.x;
    const int b = blockIdx.y;
    if (v >= NVERT) return;
    const float* c = colors + ((long long)b * NVERT + v) * 3;
    ctab[b * NVERT + v] = q8(c[0]) | (q8(c[1]) << 8) | (q8(c[2]) << 16);
}

// ---------------------------------------------------------------------------
// Prep stage 2: per-(batch,triangle) record = (rgbx0, rgbx1, rgbx2, 0) uint4.
// tab: [B,T] = 9.06 MB (1.13 MB/batch, L2-resident). Width of the record is
// irrelevant to gather cost (measured R5 vs R7) — use aligned 16 B.
// ---------------------------------------------------------------------------
__global__ __launch_bounds__(256) void build_tab(
    const int*      __restrict__ tris,  // [T,3]
    const unsigned* __restrict__ ctab,  // [B,V]
    u32x4*          __restrict__ tab)   // [B,T]
{
    const int t = blockIdx.x * blockDim.x + threadIdx.x;
    const int b = blockIdx.y;
    if (t >= NTRI) return;
    const int v0 = tris[3 * t + 0];
    const int v1 = tris[3 * t + 1];
    const int v2 = tris[3 * t + 2];
    const unsigned* cb = ctab + b * NVERT;
    u32x4 w;
    w.x = cb[v0]; w.y = cb[v1]; w.z = cb[v2]; w.w = 0u;
    tab[(long long)b * NTRI + t] = w;
}

// ---------------------------------------------------------------------------
// Main: software-pipelined. 1024 blocks x 256 thr x 4 iters x 8 px.
// Measured model (R1..R7): each divergent wave64 vmem instruction costs
// ~171 cyc of per-CU address processing regardless of width/MLP; streams
// and gathers were convoying (adding, not overlapping). Pipeline per iter:
//   1) issue 8 gathers for cur (oldest in vmcnt queue)
//   2) prefetch next iter's tids (stays in flight across the gather wait)
//   3) load cur bary (latency hides under gather wait)
//   4) compute + NT stores
// ---------------------------------------------------------------------------
__global__ __launch_bounds__(256, 4) void raster_pipe(
    const int*   __restrict__ tids,   // [B,H,W]
    const float* __restrict__ bary,   // [B,H,W,3]
    const u32x4* __restrict__ tab,    // [B,T]
    float*       __restrict__ out)    // images [B,3,H,W] ++ alphas [B,1,H,W]
{
    const int b   = blockIdx.x & 7;              // batch slice
    const int blk = blockIdx.x >> 3;             // 0..127 within batch
    const int tid = (int)threadIdx.x;
    const int base = blk * 2048 + tid;           // first quad of this thread
    const long long batch_q = (long long)b * (HWPIX / 4);

    const u32x4* tbp = tab + (long long)b * NTRI;
    float* img = out + (long long)b * (3 * HWPIX);
    float* al  = out + (long long)BATCH * 3 * HWPIX + (long long)b * HWPIX;

    // Prologue: tids for iteration 0 (two quads, 256 apart)
    i32x4 T[2][2];
    {
        const long long qg = batch_q + base;
        T[0][0] = ((const i32x4*)tids)[qg];
        T[0][1] = ((const i32x4*)tids)[qg + 256];
    }

#pragma unroll
    for (int i = 0; i < 4; ++i) {
        const int cur = i & 1, nxt = cur ^ 1;
        const int q0  = base + i * 512;          // quad index in batch
        const long long qg = batch_q + q0;

        // (1) 8 independent gathers for cur — issued first (oldest in queue)
        const int tt[8] = {T[cur][0].x, T[cur][0].y, T[cur][0].z, T[cur][0].w,
                           T[cur][1].x, T[cur][1].y, T[cur][1].z, T[cur][1].w};
        u32x4 rec[8];
#pragma unroll
        for (int j = 0; j < 8; ++j) rec[j] = tbp[tt[j]];

        // (2) prefetch next iteration's tids (independent, stays in flight)
        if (i < 3) {
            const long long qn = qg + 512;
            T[nxt][0] = ((const i32x4*)tids)[qn];
            T[nxt][1] = ((const i32x4*)tids)[qn + 256];
        }

        // (3) cur bary — latency hides under the gather wait
        f32x4 bv[6];
#pragma unroll
        for (int u = 0; u < 2; ++u)
#pragma unroll
            for (int k = 0; k < 3; ++k)
                bv[3 * u + k] = ((const f32x4*)bary)[(qg + u * 256) * 3 + k];

        // (4) compute + coalesced NT stores
#pragma unroll
        for (int u = 0; u < 2; ++u) {
            const f32x4 b0 = bv[3 * u + 0], b1 = bv[3 * u + 1], b2 = bv[3 * u + 2];
            const float w0[4] = {b0.x, b0.w, b1.z, b2.y};
            const float w1[4] = {b0.y, b1.x, b1.w, b2.z};
            const float w2[4] = {b0.z, b1.y, b2.x, b2.w};

            float r[4], g[4], bl[4], a[4];
#pragma unroll
            for (int p = 0; p < 4; ++p) {
                const u32x4 w = rec[4 * u + p];
                const float s0 = w0[p] * (1.0f / 255.0f);
                const float s1 = w1[p] * (1.0f / 255.0f);
                const float s2 = w2[p] * (1.0f / 255.0f);
                r[p]  = fminf(fmaxf((float)( w.x        & 0xff) * s0 +
                                    (float)( w.y        & 0xff) * s1 +
                                    (float)( w.z        & 0xff) * s2, 0.0f), 1.0f);
                g[p]  = fminf(fmaxf((float)((w.x >>  8) & 0xff) * s0 +
                                    (float)((w.y >>  8) & 0xff) * s1 +
                                    (float)((w.z >>  8) & 0xff) * s2, 0.0f), 1.0f);
                bl[p] = fminf(fmaxf((float)((w.x >> 16) & 0xff) * s0 +
                                    (float)((w.y >> 16) & 0xff) * s1 +
                                    (float)((w.z >> 16) & 0xff) * s2, 0.0f), 1.0f);
                a[p]  = fminf(fmaxf(2.0f * (w0[p] + w1[p] + w2[p]), 0.0f), 1.0f);
            }

            const long long s = q0 + u * 256;
            f32x4 vr = {r[0],  r[1],  r[2],  r[3]};
            f32x4 vg = {g[0],  g[1],  g[2],  g[3]};
            f32x4 vb = {bl[0], bl[1], bl[2], bl[3]};
            f32x4 va = {a[0],  a[1],  a[2],  a[3]};
            __builtin_nontemporal_store(vr, ((f32x4*)(img            )) + s);
            __builtin_nontemporal_store(vg, ((f32x4*)(img +     HWPIX)) + s);
            __builtin_nontemporal_store(vb, ((f32x4*)(img + 2 * HWPIX)) + s);
            __builtin_nontemporal_store(va, ((f32x4*)(al             )) + s);
        }
    }
}

// ---------------------------------------------------------------------------
// Fallback: direct two-level gather (R1), used only if ws is too small.
// ---------------------------------------------------------------------------
__global__ __launch_bounds__(256) void raster_kernel(
    const int*   __restrict__ tids,
    const float* __restrict__ bary,
    const float* __restrict__ colors,
    const int*   __restrict__ tris,
    float*       __restrict__ out)
{
    const long long q  = (long long)blockIdx.x * blockDim.x + threadIdx.x;
    const long long p0 = q << 2;
    const int b  = (int)(p0 >> 20);
    const int hw = (int)(p0 & (HWPIX - 1));

    const int4 t4 = ((const int4*)tids)[q];
    const float4 bv0 = ((const float4*)bary)[q * 3 + 0];
    const float4 bv1 = ((const float4*)bary)[q * 3 + 1];
    const float4 bv2 = ((const float4*)bary)[q * 3 + 2];

    const float w0[4] = {bv0.x, bv0.w, bv1.z, bv2.y};
    const float w1[4] = {bv0.y, bv1.x, bv1.w, bv2.z};
    const float w2[4] = {bv0.z, bv1.y, bv2.x, bv2.w};
    const int  tid[4] = {t4.x, t4.y, t4.z, t4.w};

    const float* __restrict__ cb = colors + (long long)b * (3 * NVERT);

    float r[4], g[4], bl[4], a[4];
#pragma unroll
    for (int i = 0; i < 4; ++i) {
        const int t  = tid[i];
        const int v0 = tris[3 * t + 0];
        const int v1 = tris[3 * t + 1];
        const int v2 = tris[3 * t + 2];
        const float* c0 = cb + 3 * v0;
        const float* c1 = cb + 3 * v1;
        const float* c2 = cb + 3 * v2;
        const float u0 = w0[i], u1 = w1[i], u2 = w2[i];
        r[i]  = fminf(fmaxf(c0[0] * u0 + c1[0] * u1 + c2[0] * u2, 0.0f), 1.0f);
        g[i]  = fminf(fmaxf(c0[1] * u0 + c1[1] * u1 + c2[1] * u2, 0.0f), 1.0f);
        bl[i] = fminf(fmaxf(c0[2] * u0 + c1[2] * u1 + c2[2] * u2, 0.0f), 1.0f);
        a[i]  = fminf(fmaxf(2.0f * (u0 + u1 + u2), 0.0f), 1.0f);
    }

    float* img = out + (long long)b * (3 * HWPIX) + hw;
    ((float4*)(img            ))[0] = make_float4(r[0],  r[1],  r[2],  r[3]);
    ((float4*)(img +     HWPIX))[0] = make_float4(g[0],  g[1],  g[2],  g[3]);
    ((float4*)(img + 2 * HWPIX))[0] = make_float4(bl[0], bl[1], bl[2], bl[3]);

    float* al = out + (long long)BATCH * 3 * HWPIX + (long long)b * HWPIX + hw;
    ((float4*)al)[0] = make_float4(a[0], a[1], a[2], a[3]);
}

extern "C" void kernel_launch(void* const* d_in, const int* in_sizes, int n_in,
                              void* d_out, int out_size, void* d_ws, size_t ws_size,
                              hipStream_t stream) {
    const int*   tids   = (const int*)  d_in[0];
    const float* bary   = (const float*)d_in[1];
    const float* colors = (const float*)d_in[2];
    const int*   tris   = (const int*)  d_in[3];
    float*       out    = (float*)      d_out;

    const size_t tab_bytes  = (size_t)BATCH * NTRI * sizeof(u32x4);     // ~9.06 MB
    const size_t ctab_bytes = (size_t)BATCH * NVERT * sizeof(unsigned); // ~1.14 MB

    if (ws_size >= tab_bytes + ctab_bytes) {
        u32x4*    tab  = (u32x4*)d_ws;
        unsigned* ctab = (unsigned*)((char*)d_ws + tab_bytes);

        dim3 g1((NVERT + 255) / 256, BATCH, 1);
        quant_colors<<<g1, 256, 0, stream>>>(colors, ctab);

        dim3 g2((NTRI + 255) / 256, BATCH, 1);
        build_tab<<<g2, 256, 0, stream>>>(tris, ctab, tab);

        raster_pipe<<<1024, 256, 0, stream>>>(tids, bary, tab, out);
    } else {
        const int quads = (BATCH * HWPIX) / 4;
        raster_kernel<<<quads / 256, 256, 0, stream>>>(tids, bary, colors, tris, out);
    }
}

// Round 10
// 270.062 us; speedup vs baseline: 1.1120x; 1.1120x over previous
//
#include <hip/hip_runtime.h>

// Problem constants: B=8, H=W=1024, V=35709, T=70789
#define BATCH 8
#define HWPIX (1024 * 1024)
#define NVERT 35709
#define NTRI  70789

typedef float        f32x4 __attribute__((ext_vector_type(4)));
typedef int          i32x4 __attribute__((ext_vector_type(4)));
typedef unsigned int u32x4 __attribute__((ext_vector_type(4)));

__device__ __forceinline__ unsigned q8(float x) {
    float v = x * 255.0f + 0.5f;
    v = fminf(fmaxf(v, 0.0f), 255.0f);
    return (unsigned)v;
}

// ---------------------------------------------------------------------------
// Prep stage 1: per-(batch,vertex) RGBX u8 color in one uint. ctab: [B,V].
// ---------------------------------------------------------------------------
__global__ __launch_bounds__(256) void quant_colors(
    const float* __restrict__ colors,   // [B,V,3]
    unsigned*    __restrict__ ctab)     // [B,V]
{
    const int v = blockIdx.x * blockDim.x + threadIdx.x;
    const int b = blockIdx.y;
    if (v >= NVERT) return;
    const float* c = colors + ((long long)b * NVERT + v) * 3;
    ctab[b * NVERT + v] = q8(c[0]) | (q8(c[1]) << 8) | (q8(c[2]) << 16);
}

// ---------------------------------------------------------------------------
// Prep stage 2: per-(batch,triangle) record = (rgbx0, rgbx1, rgbx2, 0) uint4.
// tab: [B,T] = 9.06 MB (1.13 MB/batch, L2-resident).
// ---------------------------------------------------------------------------
__global__ __launch_bounds__(256) void build_tab(
    const int*      __restrict__ tris,  // [T,3]
    const unsigned* __restrict__ ctab,  // [B,V]
    u32x4*          __restrict__ tab)   // [B,T]
{
    const int t = blockIdx.x * blockDim.x + threadIdx.x;
    const int b = blockIdx.y;
    if (t >= NTRI) return;
    const int v0 = tris[3 * t + 0];
    const int v1 = tris[3 * t + 1];
    const int v2 = tris[3 * t + 2];
    const unsigned* cb = ctab + b * NVERT;
    u32x4 w;
    w.x = cb[v0]; w.y = cb[v1]; w.z = cb[v2]; w.w = 0u;
    tab[(long long)b * NTRI + t] = w;
}

// ---------------------------------------------------------------------------
// Main (R7 shape): 4096 blocks, one thread = 2 quads 256 apart (coalesced
// 16B/lane streams, 8 px). Record gathers issued as ONE inline-asm block of
// global_load_dwordx4 ... sc0 (L1-bypass test: table is L2-resident, L1 hit
// rate ~3%). All outputs are EARLY-CLOBBER (=&v) so result VGPRs can never
// alias a not-yet-consumed address pair (the R9 fault). Block ends with
// s_waitcnt vmcnt(0); earlier tid/bary loads are drained by the same wait.
// ---------------------------------------------------------------------------
__global__ __launch_bounds__(256) void raster_sc0_kernel(
    const int*   __restrict__ tids,   // [B,H,W]
    const float* __restrict__ bary,   // [B,H,W,3]
    const u32x4* __restrict__ tab,    // [B,T]
    float*       __restrict__ out)    // images [B,3,H,W] ++ alphas [B,1,H,W]
{
    const int b   = blockIdx.x & 7;              // batch slice
    const int blk = blockIdx.x >> 3;             // 0..511 within batch
    const int tid = (int)threadIdx.x;
    const int q0  = blk * 512 + tid;             // quad index in batch (u=0)
    const long long qg0 = (long long)b * (HWPIX / 4) + q0;

    // Coalesced cached loads: 2 x int4 tids, 6 x float4 bary
    i32x4 t4[2];
    t4[0] = ((const i32x4*)tids)[qg0];
    t4[1] = ((const i32x4*)tids)[qg0 + 256];
    f32x4 bv[6];
#pragma unroll
    for (int u = 0; u < 2; ++u)
#pragma unroll
        for (int k = 0; k < 3; ++k)
            bv[3 * u + k] = ((const f32x4*)bary)[(qg0 + u * 256) * 3 + k];

    // 8 independent L1-bypass gathers in one asm block (early-clobber outs).
    const u32x4* tbp = tab + (long long)b * NTRI;
    const u32x4* p0 = tbp + t4[0].x;
    const u32x4* p1 = tbp + t4[0].y;
    const u32x4* p2 = tbp + t4[0].z;
    const u32x4* p3 = tbp + t4[0].w;
    const u32x4* p4 = tbp + t4[1].x;
    const u32x4* p5 = tbp + t4[1].y;
    const u32x4* p6 = tbp + t4[1].z;
    const u32x4* p7 = tbp + t4[1].w;
    u32x4 r0, r1, r2, r3, r4, r5, r6, r7;
    asm volatile(
        "global_load_dwordx4 %0, %8,  off sc0\n\t"
        "global_load_dwordx4 %1, %9,  off sc0\n\t"
        "global_load_dwordx4 %2, %10, off sc0\n\t"
        "global_load_dwordx4 %3, %11, off sc0\n\t"
        "global_load_dwordx4 %4, %12, off sc0\n\t"
        "global_load_dwordx4 %5, %13, off sc0\n\t"
        "global_load_dwordx4 %6, %14, off sc0\n\t"
        "global_load_dwordx4 %7, %15, off sc0\n\t"
        "s_waitcnt vmcnt(0)"
        : "=&v"(r0), "=&v"(r1), "=&v"(r2), "=&v"(r3),
          "=&v"(r4), "=&v"(r5), "=&v"(r6), "=&v"(r7)
        : "v"(p0), "v"(p1), "v"(p2), "v"(p3),
          "v"(p4), "v"(p5), "v"(p6), "v"(p7)
        : "memory");
    const u32x4 rec[8] = {r0, r1, r2, r3, r4, r5, r6, r7};

    float* img = out + (long long)b * (3 * HWPIX);
    float* al  = out + (long long)BATCH * 3 * HWPIX + (long long)b * HWPIX;

#pragma unroll
    for (int u = 0; u < 2; ++u) {
        const f32x4 b0 = bv[3 * u + 0], b1 = bv[3 * u + 1], b2 = bv[3 * u + 2];
        const float w0[4] = {b0.x, b0.w, b1.z, b2.y};
        const float w1[4] = {b0.y, b1.x, b1.w, b2.z};
        const float w2[4] = {b0.z, b1.y, b2.x, b2.w};

        float r[4], g[4], bl[4], a[4];
#pragma unroll
        for (int i = 0; i < 4; ++i) {
            const u32x4 w = rec[4 * u + i];
            const float s0 = w0[i] * (1.0f / 255.0f);
            const float s1 = w1[i] * (1.0f / 255.0f);
            const float s2 = w2[i] * (1.0f / 255.0f);
            r[i]  = fminf(fmaxf((float)( w.x        & 0xff) * s0 +
                                (float)( w.y        & 0xff) * s1 +
                                (float)( w.z        & 0xff) * s2, 0.0f), 1.0f);
            g[i]  = fminf(fmaxf((float)((w.x >>  8) & 0xff) * s0 +
                                (float)((w.y >>  8) & 0xff) * s1 +
                                (float)((w.z >>  8) & 0xff) * s2, 0.0f), 1.0f);
            bl[i] = fminf(fmaxf((float)((w.x >> 16) & 0xff) * s0 +
                                (float)((w.y >> 16) & 0xff) * s1 +
                                (float)((w.z >> 16) & 0xff) * s2, 0.0f), 1.0f);
            a[i]  = fminf(fmaxf(2.0f * (w0[i] + w1[i] + w2[i]), 0.0f), 1.0f);
        }

        const long long s = q0 + u * 256;
        f32x4 vr = {r[0],  r[1],  r[2],  r[3]};
        f32x4 vg = {g[0],  g[1],  g[2],  g[3]};
        f32x4 vb = {bl[0], bl[1], bl[2], bl[3]};
        f32x4 va = {a[0],  a[1],  a[2],  a[3]};
        __builtin_nontemporal_store(vr, ((f32x4*)(img            )) + s);
        __builtin_nontemporal_store(vg, ((f32x4*)(img +     HWPIX)) + s);
        __builtin_nontemporal_store(vb, ((f32x4*)(img + 2 * HWPIX)) + s);
        __builtin_nontemporal_store(va, ((f32x4*)(al             )) + s);
    }
}

// ---------------------------------------------------------------------------
// Fallback: direct two-level gather (R1), used only if ws is too small.
// ---------------------------------------------------------------------------
__global__ __launch_bounds__(256) void raster_kernel(
    const int*   __restrict__ tids,
    const float* __restrict__ bary,
    const float* __restrict__ colors,
    const int*   __restrict__ tris,
    float*       __restrict__ out)
{
    const long long q  = (long long)blockIdx.x * blockDim.x + threadIdx.x;
    const long long p0 = q << 2;
    const int b  = (int)(p0 >> 20);
    const int hw = (int)(p0 & (HWPIX - 1));

    const int4 t4 = ((const int4*)tids)[q];
    const float4 bv0 = ((const float4*)bary)[q * 3 + 0];
    const float4 bv1 = ((const float4*)bary)[q * 3 + 1];
    const float4 bv2 = ((const float4*)bary)[q * 3 + 2];

    const float w0[4] = {bv0.x, bv0.w, bv1.z, bv2.y};
    const float w1[4] = {bv0.y, bv1.x, bv1.w, bv2.z};
    const float w2[4] = {bv0.z, bv1.y, bv2.x, bv2.w};
    const int  tid[4] = {t4.x, t4.y, t4.z, t4.w};

    const float* __restrict__ cb = colors + (long long)b * (3 * NVERT);

    float r[4], g[4], bl[4], a[4];
#pragma unroll
    for (int i = 0; i < 4; ++i) {
        const int t  = tid[i];
        const int v0 = tris[3 * t + 0];
        const int v1 = tris[3 * t + 1];
        const int v2 = tris[3 * t + 2];
        const float* c0 = cb + 3 * v0;
        const float* c1 = cb + 3 * v1;
        const float* c2 = cb + 3 * v2;
        const float u0 = w0[i], u1 = w1[i], u2 = w2[i];
        r[i]  = fminf(fmaxf(c0[0] * u0 + c1[0] * u1 + c2[0] * u2, 0.0f), 1.0f);
        g[i]  = fminf(fmaxf(c0[1] * u0 + c1[1] * u1 + c2[1] * u2, 0.0f), 1.0f);
        bl[i] = fminf(fmaxf(c0[2] * u0 + c1[2] * u1 + c2[2] * u2, 0.0f), 1.0f);
        a[i]  = fminf(fmaxf(2.0f * (u0 + u1 + u2), 0.0f), 1.0f);
    }

    float* img = out + (long long)b * (3 * HWPIX) + hw;
    ((float4*)(img            ))[0] = make_float4(r[0],  r[1],  r[2],  r[3]);
    ((float4*)(img +     HWPIX))[0] = make_float4(g[0],  g[1],  g[2],  g[3]);
    ((float4*)(img + 2 * HWPIX))[0] = make_float4(bl[0], bl[1], bl[2], bl[3]);

    float* al = out + (long long)BATCH * 3 * HWPIX + (long long)b * HWPIX + hw;
    ((float4*)al)[0] = make_float4(a[0], a[1], a[2], a[3]);
}

extern "C" void kernel_launch(void* const* d_in, const int* in_sizes, int n_in,
                              void* d_out, int out_size, void* d_ws, size_t ws_size,
                              hipStream_t stream) {
    const int*   tids   = (const int*)  d_in[0];
    const float* bary   = (const float*)d_in[1];
    const float* colors = (const float*)d_in[2];
    const int*   tris   = (const int*)  d_in[3];
    float*       out    = (float*)      d_out;

    const size_t tab_bytes  = (size_t)BATCH * NTRI * sizeof(u32x4);     // ~9.06 MB
    const size_t ctab_bytes = (size_t)BATCH * NVERT * sizeof(unsigned); // ~1.14 MB

    if (ws_size >= tab_bytes + ctab_bytes) {
        u32x4*    tab  = (u32x4*)d_ws;
        unsigned* ctab = (unsigned*)((char*)d_ws + tab_bytes);

        dim3 g1((NVERT + 255) / 256, BATCH, 1);
        quant_colors<<<g1, 256, 0, stream>>>(colors, ctab);

        dim3 g2((NTRI + 255) / 256, BATCH, 1);
        build_tab<<<g2, 256, 0, stream>>>(tris, ctab, tab);

        const int grid = (BATCH * HWPIX) / (8 * 256);   // 4096 blocks
        raster_sc0_kernel<<<grid, 256, 0, stream>>>(tids, bary, tab, out);
    } else {
        const int quads = (BATCH * HWPIX) / 4;
        raster_kernel<<<quads / 256, 256, 0, stream>>>(tids, bary, colors, tris, out);
    }
}